// Round 1
// baseline (611.213 us; speedup 1.0000x reference)
//
#include <hip/hip_runtime.h>

#define BATCH 4
#define LEN   1024
#define KNB   30
#define CH    128
#define EIN   434

// PAIRS atom indices: N=0, Ca=1, C=2, O=3, Cb=4
__constant__ int c_pa[24] = {0,2,3,4,1,1,1,1,0,0,0,4,4,3,0,2,3,4,2,3,4,2,3,2};
__constant__ int c_pb[24] = {0,2,3,4,0,2,3,4,2,3,4,2,3,2,1,1,1,1,0,0,0,4,4,3};

struct F3 { float x, y, z; };
__device__ __forceinline__ F3 f3sub(F3 a, F3 b){ return {a.x-b.x, a.y-b.y, a.z-b.z}; }
__device__ __forceinline__ F3 f3cross(F3 a, F3 b){
  return {a.y*b.z - a.z*b.y, a.z*b.x - a.x*b.z, a.x*b.y - a.y*b.x};
}
__device__ __forceinline__ float f3dot(F3 a, F3 b){ return a.x*b.x + a.y*b.y + a.z*b.z; }
__device__ __forceinline__ F3 f3norm(F3 a){
  float n = sqrtf(f3dot(a,a));
  if (n > 0.f) return {a.x/n, a.y/n, a.z/n};
  return {0.f, 0.f, 0.f};
}
__device__ __forceinline__ float fsign(float x){ return (x > 0.f) ? 1.f : ((x < 0.f) ? -1.f : 0.f); }
__device__ __forceinline__ float clip1(float c){ return fminf(fmaxf(c, -1.f + 1e-7f), 1.f - 1e-7f); }
__device__ __forceinline__ float dihedralf(F3 ua, F3 ub, F3 uc){
  F3 n0 = f3norm(f3cross(ua, ub));
  F3 n1 = f3norm(f3cross(ub, uc));
  float cd = clip1(f3dot(n0, n1));
  F3 v = f3norm(f3cross(n0, n1));
  return fsign(-f3dot(v, ub)) * acosf(cd);
}

// Per-node: Cb, frame Qm (rows b1, n0, b1 x n0; zero at n=L-1), 22 node features.
__global__ __launch_bounds__(256) void prep_kernel(
    const float* __restrict__ X, const float* __restrict__ mask,
    float* __restrict__ wCb, float* __restrict__ wQ, float* __restrict__ wVn)
{
  int idx = blockIdx.x * 256 + threadIdx.x;
  if (idx >= BATCH * LEN) return;
  int n = idx & (LEN - 1);
  const float* p = X + (size_t)idx * 12;
  F3 Na = {p[0], p[1], p[2]};
  F3 Ca = {p[3], p[4], p[5]};
  F3 Cc = {p[6], p[7], p[8]};
  F3 Oa = {p[9], p[10], p[11]};
  F3 bv = f3sub(Ca, Na);           // b vec
  F3 cv = f3sub(Cc, Ca);           // c vec
  F3 av = f3cross(bv, cv);
  wCb[idx*3+0] = -0.58273431f*av.x + 0.56802827f*bv.x - 0.54067466f*cv.x + Ca.x;
  wCb[idx*3+1] = -0.58273431f*av.y + 0.56802827f*bv.y - 0.54067466f*cv.y + Ca.y;
  wCb[idx*3+2] = -0.58273431f*av.z + 0.56802827f*bv.z - 0.54067466f*cv.z + Ca.z;

  F3 u0 = f3norm(bv);              // U[3n]   = norm(Ca - N)
  F3 u1 = f3norm(cv);              // U[3n+1] = norm(C - Ca)

  float Q[9];
  if (n < LEN - 1){
    F3 b1 = f3norm(f3sub(u0, u1));
    F3 n0 = f3norm(f3cross(u0, u1));
    F3 r2 = f3cross(b1, n0);
    Q[0]=b1.x; Q[1]=b1.y; Q[2]=b1.z;
    Q[3]=n0.x; Q[4]=n0.y; Q[5]=n0.z;
    Q[6]=r2.x; Q[7]=r2.y; Q[8]=r2.z;
  } else {
    #pragma unroll
    for (int t = 0; t < 9; ++t) Q[t] = 0.f;
  }
  #pragma unroll
  for (int t = 0; t < 9; ++t) wQ[(size_t)idx*9 + t] = Q[t];

  float m = mask[idx];
  bool hp = (n > 0), hn = (n < LEN - 1);
  F3 um1 = {0,0,0}, u2 = {0,0,0}, u3 = {0,0,0};
  if (hp){
    const float* pp = p - 12;
    F3 Cp = {pp[6], pp[7], pp[8]};
    um1 = f3norm(f3sub(Na, Cp));   // U[3n-1] = norm(N_n - C_{n-1})
  }
  if (hn){
    const float* pn = p + 12;
    F3 Nn  = {pn[0], pn[1], pn[2]};
    F3 Can = {pn[3], pn[4], pn[5]};
    u2 = f3norm(f3sub(Nn, Cc));    // U[3n+2]
    u3 = f3norm(f3sub(Can, Nn));   // U[3n+3]
  }
  float D0=0.f, D1=0.f, D2=0.f, A0=0.f, A1=0.f, A2=0.f;
  if (hp){ D0 = dihedralf(um1, u0, u1); A0 = acosf(clip1(f3dot(um1, u0))); }
  if (hn){
    D1 = dihedralf(u0, u1, u2); A1 = acosf(clip1(f3dot(u0, u1)));
    D2 = dihedralf(u1, u2, u3); A2 = acosf(clip1(f3dot(u1, u2)));
  }
  float vn[22];
  vn[0] = cosf(D0)*m; vn[1] = cosf(D1)*m; vn[2]  = cosf(D2)*m;
  vn[3] = sinf(D0)*m; vn[4] = sinf(D1)*m; vn[5]  = sinf(D2)*m;
  vn[6] = cosf(A0)*m; vn[7] = cosf(A1)*m; vn[8]  = cosf(A2)*m;
  vn[9] = sinf(A0)*m; vn[10]= sinf(A1)*m; vn[11] = sinf(A2)*m;
  // V_direct: atoms [N, C, O] minus Xa (= N atom), rotated by Qm rows, normalized
  F3 dxs[3];
  dxs[0] = {0.f, 0.f, 0.f};
  dxs[1] = f3sub(Cc, Na);
  dxs[2] = f3sub(Oa, Na);
  #pragma unroll
  for (int a = 0; a < 3; ++a){
    F3 dv = dxs[a];
    F3 du = { Q[0]*dv.x + Q[1]*dv.y + Q[2]*dv.z,
              Q[3]*dv.x + Q[4]*dv.y + Q[5]*dv.z,
              Q[6]*dv.x + Q[7]*dv.y + Q[8]*dv.z };
    F3 dn = f3norm(du);
    vn[12 + a*3 + 0] = dn.x * m;
    vn[12 + a*3 + 1] = dn.y * m;
    vn[12 + a*3 + 2] = dn.z * m;
  }
  vn[21] = m;
  #pragma unroll
  for (int t = 0; t < 22; ++t) wVn[(size_t)idx*22 + t] = vn[t];
}

// Block per node: Ca-Ca distances + 30-round stable argmin (matches lax.top_k tie-break).
__global__ __launch_bounds__(256) void topk_kernel(
    const float* __restrict__ X, float* __restrict__ wDn,
    int* __restrict__ wIdx, float* __restrict__ outI)
{
  __shared__ float Ds[LEN];
  __shared__ unsigned long long red[4];
  int bi = blockIdx.x;
  int b  = bi >> 10;
  const float* pi = X + (size_t)bi*12 + 3;   // Ca of i
  float cx = pi[0], cy = pi[1], cz = pi[2];
  const float* Xb = X + (size_t)b * LEN * 12;
  for (int j = threadIdx.x; j < LEN; j += 256){
    const float* pj = Xb + (size_t)j*12 + 3;
    float dx = cx - pj[0], dy = cy - pj[1], dz = cz - pj[2];
    Ds[j] = sqrtf(dx*dx + dy*dy + dz*dz + 1e-6f);
  }
  __syncthreads();
  int lane = threadIdx.x & 63, wid = threadIdx.x >> 6;
  for (int k = 0; k < KNB; ++k){
    unsigned long long best = 0xFFFFFFFFFFFFFFFFull;
    for (int j = threadIdx.x; j < LEN; j += 256){
      unsigned long long key =
        ((unsigned long long)__float_as_uint(Ds[j]) << 32) | (unsigned long long)j;
      if (key < best) best = key;
    }
    #pragma unroll
    for (int off = 32; off > 0; off >>= 1){
      unsigned long long o = __shfl_down(best, off);
      if (o < best) best = o;
    }
    if (lane == 0) red[wid] = best;
    __syncthreads();
    if (threadIdx.x == 0){
      best = red[0];
      if (red[1] < best) best = red[1];
      if (red[2] < best) best = red[2];
      if (red[3] < best) best = red[3];
      int js = (int)(best & 0xFFFFFFFFull);
      wIdx[bi*KNB + k] = js;
      wDn[bi*KNB + k]  = __uint_as_float((unsigned)(best >> 32));
      outI[bi*KNB + k] = (float)js;
      Ds[js] = __uint_as_float(0x7F7FFFFFu);   // FLT_MAX: exclude
    }
    __syncthreads();
  }
}

// Block per node, 64 threads: Vn = LN(vn_raw @ W_node) * g + b
__global__ __launch_bounds__(64) void node_kernel(
    const float* __restrict__ wVn, const float* __restrict__ Wn,
    const float* __restrict__ gn, const float* __restrict__ bn,
    float* __restrict__ outV)
{
  int bi = blockIdx.x;
  int t  = threadIdx.x;
  __shared__ float v[22];
  if (t < 22) v[t] = wVn[(size_t)bi*22 + t];
  __syncthreads();
  float x0 = 0.f, x1 = 0.f;
  #pragma unroll
  for (int r = 0; r < 22; ++r){
    float vr = v[r];
    x0 = fmaf(vr, Wn[r*CH + t], x0);
    x1 = fmaf(vr, Wn[r*CH + t + 64], x1);
  }
  float s = x0 + x1;
  #pragma unroll
  for (int off = 1; off < 64; off <<= 1) s += __shfl_xor(s, off);
  float mu = s * (1.f/128.f);
  float d0 = x0 - mu, d1 = x1 - mu;
  float vs = d0*d0 + d1*d1;
  #pragma unroll
  for (int off = 1; off < 64; off <<= 1) vs += __shfl_xor(vs, off);
  float inv = 1.f / sqrtf(vs * (1.f/128.f) + 1e-5f);
  outV[(size_t)bi*CH + t]      = d0*inv*gn[t]    + bn[t];
  outV[(size_t)bi*CH + t + 64] = d1*inv*gn[t+64] + bn[t+64];
}

// Block per node, 128 threads: build 434 features x 30 edges in LDS (transposed),
// then fp32 register-tiled matmul vs W_edge + per-row LayerNorm.
__global__ __launch_bounds__(128) void edge_kernel(
    const float* __restrict__ X, const float* __restrict__ mask,
    const int* __restrict__ resi, const int* __restrict__ chain,
    const float* __restrict__ Wp, const float* __restrict__ bp,
    const float* __restrict__ We, const float* __restrict__ ge, const float* __restrict__ be,
    const float* __restrict__ wCb, const float* __restrict__ wQ,
    const float* __restrict__ wDn, const int* __restrict__ wIdx,
    float* __restrict__ outE)
{
  __shared__ __align__(16) float featT[EIN * 32];  // featT[r*32 + k], k padded to 32
  __shared__ __align__(16) float Ws[32 * CH];      // W_edge chunk, 32 rows
  __shared__ float sAI[15];     // atoms of i: N,Ca,C,O,Cb (xyz each)
  __shared__ float sQi[9];
  __shared__ float sAJ[KNB][15];
  __shared__ float sQj[KNB][9];
  __shared__ int   sOffI[KNB];
  __shared__ float sChain[KNB];
  __shared__ float sMaskJ[KNB];
  __shared__ float sDn[KNB];

  int bi  = blockIdx.x;
  int b   = bi >> 10;
  int tid = threadIdx.x;

  // zero the two pad columns
  for (int r = tid; r < EIN; r += 128){ featT[r*32 + 30] = 0.f; featT[r*32 + 31] = 0.f; }

  if (tid < KNB){
    int j  = wIdx[bi*KNB + tid];
    int gj = (b << 10) + j;
    const float* pj = X + (size_t)gj * 12;
    #pragma unroll
    for (int t = 0; t < 12; ++t) sAJ[tid][t] = pj[t];
    sAJ[tid][12] = wCb[(size_t)gj*3 + 0];
    sAJ[tid][13] = wCb[(size_t)gj*3 + 1];
    sAJ[tid][14] = wCb[(size_t)gj*3 + 2];
    #pragma unroll
    for (int t = 0; t < 9; ++t) sQj[tid][t] = wQ[(size_t)gj*9 + t];
    sOffI[tid]  = resi[bi] - resi[gj];
    sChain[tid] = (chain[bi] == chain[gj]) ? 1.f : 0.f;
    sMaskJ[tid] = mask[gj];
    sDn[tid]    = wDn[bi*KNB + tid];
  } else if (tid == KNB){
    const float* pi = X + (size_t)bi * 12;
    #pragma unroll
    for (int t = 0; t < 12; ++t) sAI[t] = pi[t];
    sAI[12] = wCb[(size_t)bi*3 + 0];
    sAI[13] = wCb[(size_t)bi*3 + 1];
    sAI[14] = wCb[(size_t)bi*3 + 2];
  } else if (tid == KNB + 1){
    #pragma unroll
    for (int t = 0; t < 9; ++t) sQi[t] = wQ[(size_t)bi*9 + t];
  }
  __syncthreads();

  // Phase A: 30 edges x 8 subtasks
  for (int t = tid; t < KNB*8; t += 128){
    int k = t >> 3, s = t & 7;
    if (s == 0){
      // positional (rows 0..15) + chain (432) + mask_j (433)
      int off = sOffI[k];
      float ch = sChain[k];
      int d = off + 32;
      d = d < 0 ? 0 : (d > 64 ? 64 : d);
      if (!(ch > 0.5f)) d = 65;
      #pragma unroll
      for (int m2 = 0; m2 < 16; ++m2)
        featT[m2*32 + k] = Wp[d*16 + m2] + bp[m2];
      featT[432*32 + k] = ch;
      featT[433*32 + k] = sMaskJ[k];
    } else if (s == 1){
      // E_direct rows 416..427: atoms [Ca,N,C,O] of j minus N_i, rotated, normalized
      float nx = sAI[0], ny = sAI[1], nz = sAI[2];
      const int amap[4] = {3, 0, 6, 9};
      #pragma unroll
      for (int a = 0; a < 4; ++a){
        float dx = sAJ[k][amap[a]+0] - nx;
        float dy = sAJ[k][amap[a]+1] - ny;
        float dz = sAJ[k][amap[a]+2] - nz;
        float e0 = sQi[0]*dx + sQi[1]*dy + sQi[2]*dz;
        float e1 = sQi[3]*dx + sQi[4]*dy + sQi[5]*dz;
        float e2 = sQi[6]*dx + sQi[7]*dy + sQi[8]*dz;
        float nn = sqrtf(e0*e0 + e1*e1 + e2*e2);
        featT[(416 + a*3 + 0)*32 + k] = nn > 0.f ? e0/nn : 0.f;
        featT[(416 + a*3 + 1)*32 + k] = nn > 0.f ? e1/nn : 0.f;
        featT[(416 + a*3 + 2)*32 + k] = nn > 0.f ? e2/nn : 0.f;
      }
    } else if (s == 2){
      // quaternion rows 428..431 from R = Qi^T * Qj
      float R[3][3];
      #pragma unroll
      for (int i2 = 0; i2 < 3; ++i2)
        #pragma unroll
        for (int l = 0; l < 3; ++l)
          R[i2][l] = sQi[0*3+i2]*sQj[k][0*3+l]
                   + sQi[1*3+i2]*sQj[k][1*3+l]
                   + sQi[2*3+i2]*sQj[k][2*3+l];
      float Rxx = R[0][0], Ryy = R[1][1], Rzz = R[2][2];
      float mx = 0.5f*sqrtf(fabsf(1.f + Rxx - Ryy - Rzz));
      float my = 0.5f*sqrtf(fabsf(1.f - Rxx + Ryy - Rzz));
      float mz = 0.5f*sqrtf(fabsf(1.f - Rxx - Ryy + Rzz));
      float qx = fsign(R[2][1] - R[1][2]) * mx;
      float qy = fsign(R[0][2] - R[2][0]) * my;
      float qz = fsign(R[1][0] - R[0][1]) * mz;
      float qw = sqrtf(fmaxf(1.f + Rxx + Ryy + Rzz, 0.f)) * 0.5f;
      float qn = sqrtf(qx*qx + qy*qy + qz*qz + qw*qw);
      featT[428*32 + k] = qn > 0.f ? qx/qn : 0.f;
      featT[429*32 + k] = qn > 0.f ? qy/qn : 0.f;
      featT[430*32 + k] = qn > 0.f ? qz/qn : 0.f;
      featT[431*32 + k] = qn > 0.f ? qw/qn : 0.f;
    }
    // RBFs rows 16..415 (p=0: Ca-Ca from topk; p>=1: PAIRS[p-1])
    for (int p = s; p < 25; p += 8){
      float d;
      if (p == 0) d = sDn[k];
      else {
        int ai = c_pa[p-1]*3, bj = c_pb[p-1]*3;
        float dx = sAI[ai+0] - sAJ[k][bj+0];
        float dy = sAI[ai+1] - sAJ[k][bj+1];
        float dz = sAI[ai+2] - sAJ[k][bj+2];
        d = sqrtf(dx*dx + dy*dy + dz*dz + 1e-6f);
      }
      #pragma unroll
      for (int m2 = 0; m2 < 16; ++m2){
        float mu = (float)(2.0 + m2 * (20.0/15.0));
        float tt = (d - mu) / 1.25f;
        featT[(16 + p*16 + m2)*32 + k] = expf(-tt*tt);
      }
    }
  }
  __syncthreads();

  // Phase B: (32-pad x 434) @ (434 x 128), thread tile 4k x 8c
  float acc[4][8];
  #pragma unroll
  for (int kk = 0; kk < 4; ++kk)
    #pragma unroll
    for (int cc = 0; cc < 8; ++cc) acc[kk][cc] = 0.f;

  int kg = tid >> 4;   // 0..7 -> k = kg*4 + kk
  int cg = tid & 15;   // 0..15 -> c = cg*8 + cc

  for (int rc = 0; rc < EIN; rc += 32){
    int rows = min(32, EIN - rc);
    {
      const float4* src = (const float4*)(We + (size_t)rc * CH);
      float4* dstW = (float4*)Ws;
      for (int e = tid; e < rows * (CH/4); e += 128) dstW[e] = src[e];
    }
    __syncthreads();
    for (int r = 0; r < rows; ++r){
      float4 a4 = *(const float4*)&featT[(rc + r)*32 + kg*4];
      float4 w0 = *(const float4*)&Ws[r*CH + cg*8];
      float4 w1 = *(const float4*)&Ws[r*CH + cg*8 + 4];
      float av[4] = {a4.x, a4.y, a4.z, a4.w};
      float wv[8] = {w0.x, w0.y, w0.z, w0.w, w1.x, w1.y, w1.z, w1.w};
      #pragma unroll
      for (int kk = 0; kk < 4; ++kk)
        #pragma unroll
        for (int cc = 0; cc < 8; ++cc)
          acc[kk][cc] = fmaf(av[kk], wv[cc], acc[kk][cc]);
    }
    __syncthreads();
  }

  // Per-edge-row LayerNorm over 128 channels (16 lanes share a row group)
  float gv[8], bv[8];
  #pragma unroll
  for (int cc = 0; cc < 8; ++cc){ gv[cc] = ge[cg*8 + cc]; bv[cc] = be[cg*8 + cc]; }
  #pragma unroll
  for (int kk = 0; kk < 4; ++kk){
    int k = kg*4 + kk;
    float s = 0.f;
    #pragma unroll
    for (int cc = 0; cc < 8; ++cc) s += acc[kk][cc];
    #pragma unroll
    for (int off = 1; off < 16; off <<= 1) s += __shfl_xor(s, off, 16);
    float mu = s * (1.f/128.f);
    float vs = 0.f;
    #pragma unroll
    for (int cc = 0; cc < 8; ++cc){ float dd = acc[kk][cc] - mu; vs += dd*dd; }
    #pragma unroll
    for (int off = 1; off < 16; off <<= 1) vs += __shfl_xor(vs, off, 16);
    float inv = 1.f / sqrtf(vs * (1.f/128.f) + 1e-5f);
    if (k < KNB){
      float o[8];
      #pragma unroll
      for (int cc = 0; cc < 8; ++cc) o[cc] = (acc[kk][cc] - mu)*inv*gv[cc] + bv[cc];
      float4* dst = (float4*)&outE[((size_t)bi*KNB + k)*CH + cg*8];
      dst[0] = make_float4(o[0], o[1], o[2], o[3]);
      dst[1] = make_float4(o[4], o[5], o[6], o[7]);
    }
  }
}

extern "C" void kernel_launch(void* const* d_in, const int* in_sizes, int n_in,
                              void* d_out, int out_size, void* d_ws, size_t ws_size,
                              hipStream_t stream)
{
  const float* X    = (const float*)d_in[0];
  const float* mask = (const float*)d_in[1];
  const int*   resi = (const int*)  d_in[2];
  const int*   chn  = (const int*)  d_in[3];
  const float* Wp   = (const float*)d_in[4];
  const float* bp   = (const float*)d_in[5];
  const float* We   = (const float*)d_in[6];
  const float* Wn   = (const float*)d_in[7];
  const float* ge   = (const float*)d_in[8];
  const float* be   = (const float*)d_in[9];
  const float* gn   = (const float*)d_in[10];
  const float* bn   = (const float*)d_in[11];

  float* outV = (float*)d_out;                          // (4,1024,128)
  float* outE = outV + (size_t)BATCH*LEN*CH;            // (4,1024,30,128)
  float* outI = outE + (size_t)BATCH*LEN*KNB*CH;        // (4,1024,30) as float

  float* ws   = (float*)d_ws;
  float* wCb  = ws;                                     // 4096*3
  float* wQ   = wCb + (size_t)BATCH*LEN*3;              // 4096*9
  float* wVn  = wQ  + (size_t)BATCH*LEN*9;              // 4096*22
  float* wDn  = wVn + (size_t)BATCH*LEN*22;             // 4096*30
  int*   wIdx = (int*)(wDn + (size_t)BATCH*LEN*KNB);    // 4096*30

  prep_kernel<<<(BATCH*LEN + 255)/256, 256, 0, stream>>>(X, mask, wCb, wQ, wVn);
  topk_kernel<<<BATCH*LEN, 256, 0, stream>>>(X, wDn, wIdx, outI);
  node_kernel<<<BATCH*LEN, 64, 0, stream>>>(wVn, Wn, gn, bn, outV);
  edge_kernel<<<BATCH*LEN, 128, 0, stream>>>(X, mask, resi, chn, Wp, bp, We, ge, be,
                                             wCb, wQ, wDn, wIdx, outE);
}

// Round 2
// 261.951 us; speedup vs baseline: 2.3333x; 2.3333x over previous
//
#include <hip/hip_runtime.h>

#define BATCH 4
#define LEN   1024
#define KNB   30
#define CH    128
#define EIN   434
#define KP    448      // padded K
#define KST   14       // k-steps of 32
#define ASTR  456      // A row stride in ushorts (padded: 228 words = 4 mod 32 banks)
#define CSTR  132      // C row stride in floats

typedef unsigned short ushort_t;
typedef __attribute__((ext_vector_type(8))) short bf16x8;
typedef __attribute__((ext_vector_type(4))) float f32x4;

// PAIRS atom indices: N=0, Ca=1, C=2, O=3, Cb=4
__constant__ int c_pa[24] = {0,2,3,4,1,1,1,1,0,0,0,4,4,3,0,2,3,4,2,3,4,2,3,2};
__constant__ int c_pb[24] = {0,2,3,4,0,2,3,4,2,3,4,2,3,2,1,1,1,1,0,0,0,4,4,3};

struct F3 { float x, y, z; };
__device__ __forceinline__ F3 f3sub(F3 a, F3 b){ return {a.x-b.x, a.y-b.y, a.z-b.z}; }
__device__ __forceinline__ F3 f3cross(F3 a, F3 b){
  return {a.y*b.z - a.z*b.y, a.z*b.x - a.x*b.z, a.x*b.y - a.y*b.x};
}
__device__ __forceinline__ float f3dot(F3 a, F3 b){ return a.x*b.x + a.y*b.y + a.z*b.z; }
__device__ __forceinline__ F3 f3norm(F3 a){
  float n = sqrtf(f3dot(a,a));
  if (n > 0.f) return {a.x/n, a.y/n, a.z/n};
  return {0.f, 0.f, 0.f};
}
__device__ __forceinline__ float fsign(float x){ return (x > 0.f) ? 1.f : ((x < 0.f) ? -1.f : 0.f); }
__device__ __forceinline__ float clip1(float c){ return fminf(fmaxf(c, -1.f + 1e-7f), 1.f - 1e-7f); }
__device__ __forceinline__ float dihedralf(F3 ua, F3 ub, F3 uc){
  F3 n0 = f3norm(f3cross(ua, ub));
  F3 n1 = f3norm(f3cross(ub, uc));
  float cd = clip1(f3dot(n0, n1));
  F3 v = f3norm(f3cross(n0, n1));
  return fsign(-f3dot(v, ub)) * acosf(cd);
}
__device__ __forceinline__ ushort_t f2bf(float f){
  unsigned u = __float_as_uint(f);
  unsigned r = u + 0x7FFFu + ((u >> 16) & 1u);   // round-to-nearest-even
  return (ushort_t)(r >> 16);
}

// ---------------------------------------------------------------------------
// Per-node: Cb, frame Qm (rows b1, n0, b1 x n0; zero at n=L-1), 22 node feats.
__global__ __launch_bounds__(256) void prep_kernel(
    const float* __restrict__ X, const float* __restrict__ mask,
    float* __restrict__ wCb, float* __restrict__ wQ, float* __restrict__ wVn)
{
  int idx = blockIdx.x * 256 + threadIdx.x;
  if (idx >= BATCH * LEN) return;
  int n = idx & (LEN - 1);
  const float* p = X + (size_t)idx * 12;
  F3 Na = {p[0], p[1], p[2]};
  F3 Ca = {p[3], p[4], p[5]};
  F3 Cc = {p[6], p[7], p[8]};
  F3 Oa = {p[9], p[10], p[11]};
  F3 bv = f3sub(Ca, Na);
  F3 cv = f3sub(Cc, Ca);
  F3 av = f3cross(bv, cv);
  wCb[idx*3+0] = -0.58273431f*av.x + 0.56802827f*bv.x - 0.54067466f*cv.x + Ca.x;
  wCb[idx*3+1] = -0.58273431f*av.y + 0.56802827f*bv.y - 0.54067466f*cv.y + Ca.y;
  wCb[idx*3+2] = -0.58273431f*av.z + 0.56802827f*bv.z - 0.54067466f*cv.z + Ca.z;

  F3 u0 = f3norm(bv);
  F3 u1 = f3norm(cv);

  float Q[9];
  if (n < LEN - 1){
    F3 b1 = f3norm(f3sub(u0, u1));
    F3 n0 = f3norm(f3cross(u0, u1));
    F3 r2 = f3cross(b1, n0);
    Q[0]=b1.x; Q[1]=b1.y; Q[2]=b1.z;
    Q[3]=n0.x; Q[4]=n0.y; Q[5]=n0.z;
    Q[6]=r2.x; Q[7]=r2.y; Q[8]=r2.z;
  } else {
    #pragma unroll
    for (int t = 0; t < 9; ++t) Q[t] = 0.f;
  }
  #pragma unroll
  for (int t = 0; t < 9; ++t) wQ[(size_t)idx*9 + t] = Q[t];

  float m = mask[idx];
  bool hp = (n > 0), hn = (n < LEN - 1);
  F3 um1 = {0,0,0}, u2 = {0,0,0}, u3 = {0,0,0};
  if (hp){
    const float* pp = p - 12;
    F3 Cp = {pp[6], pp[7], pp[8]};
    um1 = f3norm(f3sub(Na, Cp));
  }
  if (hn){
    const float* pn = p + 12;
    F3 Nn  = {pn[0], pn[1], pn[2]};
    F3 Can = {pn[3], pn[4], pn[5]};
    u2 = f3norm(f3sub(Nn, Cc));
    u3 = f3norm(f3sub(Can, Nn));
  }
  float D0=0.f, D1=0.f, D2=0.f, A0=0.f, A1=0.f, A2=0.f;
  if (hp){ D0 = dihedralf(um1, u0, u1); A0 = acosf(clip1(f3dot(um1, u0))); }
  if (hn){
    D1 = dihedralf(u0, u1, u2); A1 = acosf(clip1(f3dot(u0, u1)));
    D2 = dihedralf(u1, u2, u3); A2 = acosf(clip1(f3dot(u1, u2)));
  }
  float vn[22];
  vn[0] = cosf(D0)*m; vn[1] = cosf(D1)*m; vn[2]  = cosf(D2)*m;
  vn[3] = sinf(D0)*m; vn[4] = sinf(D1)*m; vn[5]  = sinf(D2)*m;
  vn[6] = cosf(A0)*m; vn[7] = cosf(A1)*m; vn[8]  = cosf(A2)*m;
  vn[9] = sinf(A0)*m; vn[10]= sinf(A1)*m; vn[11] = sinf(A2)*m;
  F3 dxs[3];
  dxs[0] = {0.f, 0.f, 0.f};
  dxs[1] = f3sub(Cc, Na);
  dxs[2] = f3sub(Oa, Na);
  #pragma unroll
  for (int a = 0; a < 3; ++a){
    F3 dv = dxs[a];
    F3 du = { Q[0]*dv.x + Q[1]*dv.y + Q[2]*dv.z,
              Q[3]*dv.x + Q[4]*dv.y + Q[5]*dv.z,
              Q[6]*dv.x + Q[7]*dv.y + Q[8]*dv.z };
    F3 dn = f3norm(du);
    vn[12 + a*3 + 0] = dn.x * m;
    vn[12 + a*3 + 1] = dn.y * m;
    vn[12 + a*3 + 2] = dn.z * m;
  }
  vn[21] = m;
  #pragma unroll
  for (int t = 0; t < 22; ++t) wVn[(size_t)idx*22 + t] = vn[t];
}

// ---------------------------------------------------------------------------
// Block per node: Ca-Ca distances + 30-round stable argmin (lax.top_k order).
__global__ __launch_bounds__(256) void topk_kernel(
    const float* __restrict__ X, float* __restrict__ wDn,
    int* __restrict__ wIdx, float* __restrict__ outI)
{
  __shared__ float Ds[LEN];
  __shared__ unsigned long long red[4];
  int bi = blockIdx.x;
  int b  = bi >> 10;
  const float* pi = X + (size_t)bi*12 + 3;
  float cx = pi[0], cy = pi[1], cz = pi[2];
  const float* Xb = X + (size_t)b * LEN * 12;
  for (int j = threadIdx.x; j < LEN; j += 256){
    const float* pj = Xb + (size_t)j*12 + 3;
    float dx = cx - pj[0], dy = cy - pj[1], dz = cz - pj[2];
    Ds[j] = sqrtf(dx*dx + dy*dy + dz*dz + 1e-6f);
  }
  __syncthreads();
  int lane = threadIdx.x & 63, wid = threadIdx.x >> 6;
  for (int k = 0; k < KNB; ++k){
    unsigned long long best = 0xFFFFFFFFFFFFFFFFull;
    for (int j = threadIdx.x; j < LEN; j += 256){
      unsigned long long key =
        ((unsigned long long)__float_as_uint(Ds[j]) << 32) | (unsigned long long)j;
      if (key < best) best = key;
    }
    #pragma unroll
    for (int off = 32; off > 0; off >>= 1){
      unsigned long long o = __shfl_down(best, off);
      if (o < best) best = o;
    }
    if (lane == 0) red[wid] = best;
    __syncthreads();
    if (threadIdx.x == 0){
      best = red[0];
      if (red[1] < best) best = red[1];
      if (red[2] < best) best = red[2];
      if (red[3] < best) best = red[3];
      int js = (int)(best & 0xFFFFFFFFull);
      wIdx[bi*KNB + k] = js;
      wDn[bi*KNB + k]  = __uint_as_float((unsigned)(best >> 32));
      outI[bi*KNB + k] = (float)js;
      Ds[js] = __uint_as_float(0x7F7FFFFFu);
    }
    __syncthreads();
  }
}

// ---------------------------------------------------------------------------
// Vn = LN(vn_raw @ W_node) * g + b
__global__ __launch_bounds__(64) void node_kernel(
    const float* __restrict__ wVn, const float* __restrict__ Wn,
    const float* __restrict__ gn, const float* __restrict__ bn,
    float* __restrict__ outV)
{
  int bi = blockIdx.x;
  int t  = threadIdx.x;
  __shared__ float v[22];
  if (t < 22) v[t] = wVn[(size_t)bi*22 + t];
  __syncthreads();
  float x0 = 0.f, x1 = 0.f;
  #pragma unroll
  for (int r = 0; r < 22; ++r){
    float vr = v[r];
    x0 = fmaf(vr, Wn[r*CH + t], x0);
    x1 = fmaf(vr, Wn[r*CH + t + 64], x1);
  }
  float s = x0 + x1;
  #pragma unroll
  for (int off = 1; off < 64; off <<= 1) s += __shfl_xor(s, off);
  float mu = s * (1.f/128.f);
  float d0 = x0 - mu, d1 = x1 - mu;
  float vs = d0*d0 + d1*d1;
  #pragma unroll
  for (int off = 1; off < 64; off <<= 1) vs += __shfl_xor(vs, off);
  float inv = 1.f / sqrtf(vs * (1.f/128.f) + 1e-5f);
  outV[(size_t)bi*CH + t]      = d0*inv*gn[t]    + bn[t];
  outV[(size_t)bi*CH + t + 64] = d1*inv*gn[t+64] + bn[t+64];
}

// ---------------------------------------------------------------------------
// Pack W_edge (434x128 f32) into bf16 B-fragment-linear order:
// Wfrag[ntile(8)][kstep(14)][lane(64)][j(8)], n = t*16+(l&15), k = s*32+(l>>4)*8+j
__global__ __launch_bounds__(256) void wpack_kernel(
    const float* __restrict__ We, ushort_t* __restrict__ Wfrag)
{
  int f = blockIdx.x*256 + threadIdx.x;
  if (f >= 8*KST*64) return;
  int t = f / (KST*64);
  int s = (f / 64) % KST;
  int l = f & 63;
  int n  = t*16 + (l & 15);
  int k0 = s*32 + (l >> 4)*8;
  ushort_t v[8];
  #pragma unroll
  for (int j = 0; j < 8; ++j){
    int k = k0 + j;
    v[j] = (k < EIN) ? f2bf(We[(size_t)k*CH + n]) : (ushort_t)0;
  }
  ulong2* dst = (ulong2*)(Wfrag + (size_t)f*8);
  *dst = *(ulong2*)v;
}

// ---------------------------------------------------------------------------
// Block per node, 256 threads: build 30x434 features as bf16 A-tile in LDS,
// then MFMA (16x16x32 bf16) vs pre-packed W fragments + LayerNorm epilogue.
__global__ __launch_bounds__(256) void edge_kernel(
    const float* __restrict__ X, const float* __restrict__ mask,
    const int* __restrict__ resi, const int* __restrict__ chain,
    const float* __restrict__ Wp, const float* __restrict__ bp,
    const float* __restrict__ ge, const float* __restrict__ be,
    const float* __restrict__ wCb, const float* __restrict__ wQ,
    const float* __restrict__ wDn, const int* __restrict__ wIdx,
    const ushort_t* __restrict__ Wfrag,
    float* __restrict__ outE)
{
  __shared__ __align__(16) ushort_t As[32*ASTR];   // 29184 B, reused as C (f32) later
  __shared__ float sAI[15];
  __shared__ float sQi[9];
  __shared__ float sAJ[KNB][15];
  __shared__ float sQj[KNB][9];
  __shared__ int   sOffI[KNB];
  __shared__ float sChain[KNB];
  __shared__ float sMaskJ[KNB];
  __shared__ float sDn[KNB];

  int bi  = blockIdx.x;
  int b   = bi >> 10;
  int tid = threadIdx.x;

  if (tid < KNB){
    int j  = wIdx[bi*KNB + tid];
    int gj = (b << 10) + j;
    const float* pj = X + (size_t)gj * 12;
    #pragma unroll
    for (int t = 0; t < 12; ++t) sAJ[tid][t] = pj[t];
    sAJ[tid][12] = wCb[(size_t)gj*3 + 0];
    sAJ[tid][13] = wCb[(size_t)gj*3 + 1];
    sAJ[tid][14] = wCb[(size_t)gj*3 + 2];
    #pragma unroll
    for (int t = 0; t < 9; ++t) sQj[tid][t] = wQ[(size_t)gj*9 + t];
    sOffI[tid]  = resi[bi] - resi[gj];
    sChain[tid] = (chain[bi] == chain[gj]) ? 1.f : 0.f;
    sMaskJ[tid] = mask[gj];
    sDn[tid]    = wDn[bi*KNB + tid];
  } else if (tid == KNB){
    const float* pi = X + (size_t)bi * 12;
    #pragma unroll
    for (int t = 0; t < 12; ++t) sAI[t] = pi[t];
    sAI[12] = wCb[(size_t)bi*3 + 0];
    sAI[13] = wCb[(size_t)bi*3 + 1];
    sAI[14] = wCb[(size_t)bi*3 + 2];
  } else if (tid == KNB + 1){
    #pragma unroll
    for (int t = 0; t < 9; ++t) sQi[t] = wQ[(size_t)bi*9 + t];
  }
  // zero pad: rows 30,31 (448 cols) and cols 434..447 of rows 0..29
  for (int e = tid; e < 2*KP; e += 256) As[30*ASTR + (e >= KP ? ASTR + e - KP : e)] = 0;
  for (int e = tid; e < KNB*14; e += 256){
    int r = e / 14, c = EIN + (e % 14);
    As[r*ASTR + c] = 0;
  }
  __syncthreads();

  // Phase A: 30 edges x 8 subtasks, writing bf16 features edge-major
  if (tid < KNB*8){
    int k = tid >> 3, s = tid & 7;
    ushort_t* row = &As[k*ASTR];
    if (s == 0){
      int off = sOffI[k];
      float ch = sChain[k];
      int d = off + 32;
      d = d < 0 ? 0 : (d > 64 ? 64 : d);
      if (!(ch > 0.5f)) d = 65;
      #pragma unroll
      for (int m2 = 0; m2 < 16; ++m2)
        row[m2] = f2bf(Wp[d*16 + m2] + bp[m2]);
      row[432] = f2bf(ch);
      row[433] = f2bf(sMaskJ[k]);
    } else if (s == 1){
      float nx = sAI[0], ny = sAI[1], nz = sAI[2];
      const int amap[4] = {3, 0, 6, 9};
      #pragma unroll
      for (int a = 0; a < 4; ++a){
        float dx = sAJ[k][amap[a]+0] - nx;
        float dy = sAJ[k][amap[a]+1] - ny;
        float dz = sAJ[k][amap[a]+2] - nz;
        float e0 = sQi[0]*dx + sQi[1]*dy + sQi[2]*dz;
        float e1 = sQi[3]*dx + sQi[4]*dy + sQi[5]*dz;
        float e2 = sQi[6]*dx + sQi[7]*dy + sQi[8]*dz;
        float nn = sqrtf(e0*e0 + e1*e1 + e2*e2);
        float inv = nn > 0.f ? 1.f/nn : 0.f;
        row[416 + a*3 + 0] = f2bf(e0*inv);
        row[416 + a*3 + 1] = f2bf(e1*inv);
        row[416 + a*3 + 2] = f2bf(e2*inv);
      }
    } else if (s == 2){
      float R[3][3];
      #pragma unroll
      for (int i2 = 0; i2 < 3; ++i2)
        #pragma unroll
        for (int l2 = 0; l2 < 3; ++l2)
          R[i2][l2] = sQi[0*3+i2]*sQj[k][0*3+l2]
                    + sQi[1*3+i2]*sQj[k][1*3+l2]
                    + sQi[2*3+i2]*sQj[k][2*3+l2];
      float Rxx = R[0][0], Ryy = R[1][1], Rzz = R[2][2];
      float mx = 0.5f*sqrtf(fabsf(1.f + Rxx - Ryy - Rzz));
      float my = 0.5f*sqrtf(fabsf(1.f - Rxx + Ryy - Rzz));
      float mz = 0.5f*sqrtf(fabsf(1.f - Rxx - Ryy + Rzz));
      float qx = fsign(R[2][1] - R[1][2]) * mx;
      float qy = fsign(R[0][2] - R[2][0]) * my;
      float qz = fsign(R[1][0] - R[0][1]) * mz;
      float qw = sqrtf(fmaxf(1.f + Rxx + Ryy + Rzz, 0.f)) * 0.5f;
      float qn = sqrtf(qx*qx + qy*qy + qz*qz + qw*qw);
      float inv = qn > 0.f ? 1.f/qn : 0.f;
      row[428] = f2bf(qx*inv);
      row[429] = f2bf(qy*inv);
      row[430] = f2bf(qz*inv);
      row[431] = f2bf(qw*inv);
    }
    for (int p = s; p < 25; p += 8){
      float d;
      if (p == 0) d = sDn[k];
      else {
        int ai = c_pa[p-1]*3, bj = c_pb[p-1]*3;
        float dx = sAI[ai+0] - sAJ[k][bj+0];
        float dy = sAI[ai+1] - sAJ[k][bj+1];
        float dz = sAI[ai+2] - sAJ[k][bj+2];
        d = sqrtf(dx*dx + dy*dy + dz*dz + 1e-6f);
      }
      #pragma unroll
      for (int m2 = 0; m2 < 16; ++m2){
        float mu = (float)(2.0 + m2 * (20.0/15.0));
        float tt = (d - mu) * 0.8f;
        row[16 + p*16 + m2] = f2bf(expf(-tt*tt));
      }
    }
  }
  __syncthreads();

  // Phase B: MFMA. wave w owns ntiles {2w,2w+1} x mtiles {0,1}
  int w = tid >> 6, l = tid & 63;
  int n0 = w*2;
  int aOff0 = (l & 15)*ASTR + (l >> 4)*8;          // mtile 0
  int aOff1 = aOff0 + 16*ASTR;                     // mtile 1
  const ushort_t* bp0 = Wfrag + ((size_t)(n0    *KST)*64 + l)*8;
  const ushort_t* bp1 = Wfrag + ((size_t)((n0+1)*KST)*64 + l)*8;

  f32x4 acc00 = {0.f,0.f,0.f,0.f}, acc01 = acc00, acc10 = acc00, acc11 = acc00;

  bf16x8 a0 = *(const bf16x8*)&As[aOff0];
  bf16x8 a1 = *(const bf16x8*)&As[aOff1];
  bf16x8 b0 = *(const bf16x8*)bp0;
  bf16x8 b1 = *(const bf16x8*)bp1;
  #pragma unroll
  for (int s = 0; s < KST; ++s){
    bf16x8 a0n, a1n, b0n, b1n;
    if (s < KST-1){
      int ka = (s+1)*32;
      a0n = *(const bf16x8*)&As[aOff0 + ka];
      a1n = *(const bf16x8*)&As[aOff1 + ka];
      b0n = *(const bf16x8*)(bp0 + (size_t)(s+1)*64*8);
      b1n = *(const bf16x8*)(bp1 + (size_t)(s+1)*64*8);
    }
    acc00 = __builtin_amdgcn_mfma_f32_16x16x32_bf16(a0, b0, acc00, 0, 0, 0);
    acc01 = __builtin_amdgcn_mfma_f32_16x16x32_bf16(a0, b1, acc01, 0, 0, 0);
    acc10 = __builtin_amdgcn_mfma_f32_16x16x32_bf16(a1, b0, acc10, 0, 0, 0);
    acc11 = __builtin_amdgcn_mfma_f32_16x16x32_bf16(a1, b1, acc11, 0, 0, 0);
    if (s < KST-1){ a0 = a0n; a1 = a1n; b0 = b0n; b1 = b1n; }
  }
  __syncthreads();   // all As reads done; reuse as C tile

  float* Cs = (float*)As;       // [32][CSTR]
  int ccol = l & 15, crow = (l >> 4)*4;
  #pragma unroll
  for (int r = 0; r < 4; ++r){
    Cs[(crow + r)*CSTR      + n0*16 + ccol]      = acc00[r];
    Cs[(crow + r)*CSTR      + (n0+1)*16 + ccol]  = acc01[r];
    Cs[(16 + crow + r)*CSTR + n0*16 + ccol]      = acc10[r];
    Cs[(16 + crow + r)*CSTR + (n0+1)*16 + ccol]  = acc11[r];
  }
  __syncthreads();

  // LayerNorm: 8 threads per edge row, 16 channels each
  if (tid < KNB*8){
    int row = tid >> 3, g = tid & 7;
    float v[16];
    #pragma unroll
    for (int c = 0; c < 16; ++c) v[c] = Cs[row*CSTR + g*16 + c];
    float s = 0.f;
    #pragma unroll
    for (int c = 0; c < 16; ++c) s += v[c];
    #pragma unroll
    for (int off = 1; off < 8; off <<= 1) s += __shfl_xor(s, off, 8);
    float mu = s * (1.f/128.f);
    float vs = 0.f;
    #pragma unroll
    for (int c = 0; c < 16; ++c){ float dd = v[c] - mu; vs += dd*dd; }
    #pragma unroll
    for (int off = 1; off < 8; off <<= 1) vs += __shfl_xor(vs, off, 8);
    float inv = 1.f / sqrtf(vs * (1.f/128.f) + 1e-5f);
    float o[16];
    #pragma unroll
    for (int c = 0; c < 16; ++c)
      o[c] = (v[c] - mu)*inv*ge[g*16 + c] + be[g*16 + c];
    float4* dst = (float4*)&outE[((size_t)bi*KNB + row)*CH + g*16];
    dst[0] = make_float4(o[0], o[1], o[2], o[3]);
    dst[1] = make_float4(o[4], o[5], o[6], o[7]);
    dst[2] = make_float4(o[8], o[9], o[10], o[11]);
    dst[3] = make_float4(o[12], o[13], o[14], o[15]);
  }
}

extern "C" void kernel_launch(void* const* d_in, const int* in_sizes, int n_in,
                              void* d_out, int out_size, void* d_ws, size_t ws_size,
                              hipStream_t stream)
{
  const float* X    = (const float*)d_in[0];
  const float* mask = (const float*)d_in[1];
  const int*   resi = (const int*)  d_in[2];
  const int*   chn  = (const int*)  d_in[3];
  const float* Wp   = (const float*)d_in[4];
  const float* bp   = (const float*)d_in[5];
  const float* We   = (const float*)d_in[6];
  const float* Wn   = (const float*)d_in[7];
  const float* ge   = (const float*)d_in[8];
  const float* be   = (const float*)d_in[9];
  const float* gn   = (const float*)d_in[10];
  const float* bn   = (const float*)d_in[11];

  float* outV = (float*)d_out;                          // (4,1024,128)
  float* outE = outV + (size_t)BATCH*LEN*CH;            // (4,1024,30,128)
  float* outI = outE + (size_t)BATCH*LEN*KNB*CH;        // (4,1024,30) as float

  float* ws   = (float*)d_ws;
  float* wCb  = ws;                                     // 4096*3
  float* wQ   = wCb + (size_t)BATCH*LEN*3;              // 4096*9
  float* wVn  = wQ  + (size_t)BATCH*LEN*9;              // 4096*22
  float* wDn  = wVn + (size_t)BATCH*LEN*22;             // 4096*30
  int*   wIdx = (int*)(wDn + (size_t)BATCH*LEN*KNB);    // 4096*30
  ushort_t* Wfrag = (ushort_t*)(wIdx + (size_t)BATCH*LEN*KNB);  // 8*14*64*8 bf16

  wpack_kernel<<<(8*KST*64 + 255)/256, 256, 0, stream>>>(We, Wfrag);
  prep_kernel<<<(BATCH*LEN + 255)/256, 256, 0, stream>>>(X, mask, wCb, wQ, wVn);
  topk_kernel<<<BATCH*LEN, 256, 0, stream>>>(X, wDn, wIdx, outI);
  node_kernel<<<BATCH*LEN, 64, 0, stream>>>(wVn, Wn, gn, bn, outV);
  edge_kernel<<<BATCH*LEN, 256, 0, stream>>>(X, mask, resi, chn, Wp, bp, ge, be,
                                             wCb, wQ, wDn, wIdx, Wfrag, outE);
}

// Round 3
// 253.327 us; speedup vs baseline: 2.4127x; 1.0340x over previous
//
#include <hip/hip_runtime.h>

#define BATCH 4
#define LEN   1024
#define KNB   30
#define CH    128
#define EIN   434
#define KP    448      // padded K
#define KST   14       // k-steps of 32
#define ASTR  456      // A row stride in ushorts (padded: 228 words = 4 mod 32 banks)
#define CSTR  132      // C row stride in floats

typedef unsigned short ushort_t;
typedef __attribute__((ext_vector_type(8))) short bf16x8;
typedef __attribute__((ext_vector_type(4))) float f32x4;

// PAIRS atom indices: N=0, Ca=1, C=2, O=3, Cb=4
__constant__ int c_pa[24] = {0,2,3,4,1,1,1,1,0,0,0,4,4,3,0,2,3,4,2,3,4,2,3,2};
__constant__ int c_pb[24] = {0,2,3,4,0,2,3,4,2,3,4,2,3,2,1,1,1,1,0,0,0,4,4,3};

struct F3 { float x, y, z; };
__device__ __forceinline__ F3 f3sub(F3 a, F3 b){ return {a.x-b.x, a.y-b.y, a.z-b.z}; }
__device__ __forceinline__ F3 f3cross(F3 a, F3 b){
  return {a.y*b.z - a.z*b.y, a.z*b.x - a.x*b.z, a.x*b.y - a.y*b.x};
}
__device__ __forceinline__ float f3dot(F3 a, F3 b){ return a.x*b.x + a.y*b.y + a.z*b.z; }
__device__ __forceinline__ F3 f3norm(F3 a){
  float n = sqrtf(f3dot(a,a));
  if (n > 0.f) return {a.x/n, a.y/n, a.z/n};
  return {0.f, 0.f, 0.f};
}
__device__ __forceinline__ float fsign(float x){ return (x > 0.f) ? 1.f : ((x < 0.f) ? -1.f : 0.f); }
__device__ __forceinline__ float clip1(float c){ return fminf(fmaxf(c, -1.f + 1e-7f), 1.f - 1e-7f); }
__device__ __forceinline__ float dihedralf(F3 ua, F3 ub, F3 uc){
  F3 n0 = f3norm(f3cross(ua, ub));
  F3 n1 = f3norm(f3cross(ub, uc));
  float cd = clip1(f3dot(n0, n1));
  F3 v = f3norm(f3cross(n0, n1));
  return fsign(-f3dot(v, ub)) * acosf(cd);
}
__device__ __forceinline__ ushort_t f2bf(float f){
  unsigned u = __float_as_uint(f);
  unsigned r = u + 0x7FFFu + ((u >> 16) & 1u);   // round-to-nearest-even
  return (ushort_t)(r >> 16);
}

// ---------------------------------------------------------------------------
// Blocks 0..15: per-node prep (Cb, frame Q, node feats, packed Ca).
// Blocks 16..43: pack W_edge into bf16 B-fragment order.
__global__ __launch_bounds__(256) void prep_kernel(
    const float* __restrict__ X, const float* __restrict__ mask,
    const float* __restrict__ We,
    float* __restrict__ wCb, float* __restrict__ wQ, float* __restrict__ wVn,
    float* __restrict__ wCa, ushort_t* __restrict__ Wfrag)
{
  if (blockIdx.x >= 16){
    int f = (blockIdx.x - 16)*256 + threadIdx.x;
    if (f >= 8*KST*64) return;
    int t = f / (KST*64);
    int s = (f / 64) % KST;
    int l = f & 63;
    int n  = t*16 + (l & 15);
    int k0 = s*32 + (l >> 4)*8;
    ushort_t v[8];
    #pragma unroll
    for (int j = 0; j < 8; ++j){
      int k = k0 + j;
      v[j] = (k < EIN) ? f2bf(We[(size_t)k*CH + n]) : (ushort_t)0;
    }
    ulong2* dst = (ulong2*)(Wfrag + (size_t)f*8);
    *dst = *(ulong2*)v;
    return;
  }

  int idx = blockIdx.x * 256 + threadIdx.x;
  int n = idx & (LEN - 1);
  const float* p = X + (size_t)idx * 12;
  F3 Na = {p[0], p[1], p[2]};
  F3 Ca = {p[3], p[4], p[5]};
  F3 Cc = {p[6], p[7], p[8]};
  F3 Oa = {p[9], p[10], p[11]};
  wCa[idx*4+0] = Ca.x; wCa[idx*4+1] = Ca.y; wCa[idx*4+2] = Ca.z; wCa[idx*4+3] = 0.f;
  F3 bv = f3sub(Ca, Na);
  F3 cv = f3sub(Cc, Ca);
  F3 av = f3cross(bv, cv);
  wCb[idx*3+0] = -0.58273431f*av.x + 0.56802827f*bv.x - 0.54067466f*cv.x + Ca.x;
  wCb[idx*3+1] = -0.58273431f*av.y + 0.56802827f*bv.y - 0.54067466f*cv.y + Ca.y;
  wCb[idx*3+2] = -0.58273431f*av.z + 0.56802827f*bv.z - 0.54067466f*cv.z + Ca.z;

  F3 u0 = f3norm(bv);
  F3 u1 = f3norm(cv);

  float Q[9];
  if (n < LEN - 1){
    F3 b1 = f3norm(f3sub(u0, u1));
    F3 n0 = f3norm(f3cross(u0, u1));
    F3 r2 = f3cross(b1, n0);
    Q[0]=b1.x; Q[1]=b1.y; Q[2]=b1.z;
    Q[3]=n0.x; Q[4]=n0.y; Q[5]=n0.z;
    Q[6]=r2.x; Q[7]=r2.y; Q[8]=r2.z;
  } else {
    #pragma unroll
    for (int t = 0; t < 9; ++t) Q[t] = 0.f;
  }
  #pragma unroll
  for (int t = 0; t < 9; ++t) wQ[(size_t)idx*9 + t] = Q[t];

  float m = mask[idx];
  bool hp = (n > 0), hn = (n < LEN - 1);
  F3 um1 = {0,0,0}, u2 = {0,0,0}, u3 = {0,0,0};
  if (hp){
    const float* pp = p - 12;
    F3 Cp = {pp[6], pp[7], pp[8]};
    um1 = f3norm(f3sub(Na, Cp));
  }
  if (hn){
    const float* pn = p + 12;
    F3 Nn  = {pn[0], pn[1], pn[2]};
    F3 Can = {pn[3], pn[4], pn[5]};
    u2 = f3norm(f3sub(Nn, Cc));
    u3 = f3norm(f3sub(Can, Nn));
  }
  float D0=0.f, D1=0.f, D2=0.f, A0=0.f, A1=0.f, A2=0.f;
  if (hp){ D0 = dihedralf(um1, u0, u1); A0 = acosf(clip1(f3dot(um1, u0))); }
  if (hn){
    D1 = dihedralf(u0, u1, u2); A1 = acosf(clip1(f3dot(u0, u1)));
    D2 = dihedralf(u1, u2, u3); A2 = acosf(clip1(f3dot(u1, u2)));
  }
  float vn[22];
  vn[0] = cosf(D0)*m; vn[1] = cosf(D1)*m; vn[2]  = cosf(D2)*m;
  vn[3] = sinf(D0)*m; vn[4] = sinf(D1)*m; vn[5]  = sinf(D2)*m;
  vn[6] = cosf(A0)*m; vn[7] = cosf(A1)*m; vn[8]  = cosf(A2)*m;
  vn[9] = sinf(A0)*m; vn[10]= sinf(A1)*m; vn[11] = sinf(A2)*m;
  F3 dxs[3];
  dxs[0] = {0.f, 0.f, 0.f};
  dxs[1] = f3sub(Cc, Na);
  dxs[2] = f3sub(Oa, Na);
  #pragma unroll
  for (int a = 0; a < 3; ++a){
    F3 dv = dxs[a];
    F3 du = { Q[0]*dv.x + Q[1]*dv.y + Q[2]*dv.z,
              Q[3]*dv.x + Q[4]*dv.y + Q[5]*dv.z,
              Q[6]*dv.x + Q[7]*dv.y + Q[8]*dv.z };
    F3 dn = f3norm(du);
    vn[12 + a*3 + 0] = dn.x * m;
    vn[12 + a*3 + 1] = dn.y * m;
    vn[12 + a*3 + 2] = dn.z * m;
  }
  vn[21] = m;
  #pragma unroll
  for (int t = 0; t < 22; ++t) wVn[(size_t)idx*22 + t] = vn[t];
}

// ---------------------------------------------------------------------------
// Wave-per-node top-30: 16 register-resident u64 keys per lane,
// 30 rounds of 64-bit wave argmin. No LDS, no barriers.
// Key = (f32bits(D)<<32)|j -> exact lax.top_k (value, then lower-index) order.
__global__ __launch_bounds__(256) void topk_kernel(
    const float* __restrict__ wCa, float* __restrict__ wDn,
    int* __restrict__ wIdx, float* __restrict__ outI)
{
  int wid = threadIdx.x >> 6, l = threadIdx.x & 63;
  int bi = blockIdx.x*4 + wid;
  int b  = bi >> 10;
  const float4* Ca = (const float4*)wCa;
  float4 ci = Ca[bi];
  const float4* Cb = Ca + (size_t)b * LEN;

  unsigned long long key[16];
  #pragma unroll
  for (int t = 0; t < 16; ++t){
    int j = l + 64*t;
    float4 cj = Cb[j];
    float dx = ci.x - cj.x, dy = ci.y - cj.y, dz = ci.z - cj.z;
    float D = sqrtf(dx*dx + dy*dy + dz*dz + 1e-6f);
    key[t] = ((unsigned long long)__float_as_uint(D) << 32) | (unsigned)j;
  }
  unsigned long long lmin = key[0];
  #pragma unroll
  for (int t = 1; t < 16; ++t) lmin = key[t] < lmin ? key[t] : lmin;

  for (int k = 0; k < KNB; ++k){
    unsigned long long g = lmin;
    #pragma unroll
    for (int off = 32; off > 0; off >>= 1){
      unsigned long long o = __shfl_xor(g, off);
      g = o < g ? o : g;
    }
    if (lmin == g){
      int j = (int)(g & 0xFFFFFFFFull);
      wIdx[bi*KNB + k] = j;
      wDn[bi*KNB + k]  = __uint_as_float((unsigned)(g >> 32));
      outI[bi*KNB + k] = (float)j;
      int tw = j >> 6;
      #pragma unroll
      for (int t = 0; t < 16; ++t) if (t == tw) key[t] = ~0ull;
      lmin = key[0];
      #pragma unroll
      for (int t = 1; t < 16; ++t) lmin = key[t] < lmin ? key[t] : lmin;
    }
  }
}

// ---------------------------------------------------------------------------
// Vn = LN(vn_raw @ W_node) * g + b
__global__ __launch_bounds__(64) void node_kernel(
    const float* __restrict__ wVn, const float* __restrict__ Wn,
    const float* __restrict__ gn, const float* __restrict__ bn,
    float* __restrict__ outV)
{
  int bi = blockIdx.x;
  int t  = threadIdx.x;
  __shared__ float v[22];
  if (t < 22) v[t] = wVn[(size_t)bi*22 + t];
  __syncthreads();
  float x0 = 0.f, x1 = 0.f;
  #pragma unroll
  for (int r = 0; r < 22; ++r){
    float vr = v[r];
    x0 = fmaf(vr, Wn[r*CH + t], x0);
    x1 = fmaf(vr, Wn[r*CH + t + 64], x1);
  }
  float s = x0 + x1;
  #pragma unroll
  for (int off = 1; off < 64; off <<= 1) s += __shfl_xor(s, off);
  float mu = s * (1.f/128.f);
  float d0 = x0 - mu, d1 = x1 - mu;
  float vs = d0*d0 + d1*d1;
  #pragma unroll
  for (int off = 1; off < 64; off <<= 1) vs += __shfl_xor(vs, off);
  float inv = 1.f / sqrtf(vs * (1.f/128.f) + 1e-5f);
  outV[(size_t)bi*CH + t]      = d0*inv*gn[t]    + bn[t];
  outV[(size_t)bi*CH + t + 64] = d1*inv*gn[t+64] + bn[t+64];
}

// ---------------------------------------------------------------------------
// Block per node, 256 threads: build 30x434 features as bf16 A-tile in LDS,
// then MFMA (16x16x32 bf16) vs pre-packed W fragments + LayerNorm epilogue.
__global__ __launch_bounds__(256) void edge_kernel(
    const float* __restrict__ X, const float* __restrict__ mask,
    const int* __restrict__ resi, const int* __restrict__ chain,
    const float* __restrict__ Wp, const float* __restrict__ bp,
    const float* __restrict__ ge, const float* __restrict__ be,
    const float* __restrict__ wCb, const float* __restrict__ wQ,
    const float* __restrict__ wDn, const int* __restrict__ wIdx,
    const ushort_t* __restrict__ Wfrag,
    float* __restrict__ outE)
{
  __shared__ __align__(16) ushort_t As[32*ASTR];   // 29184 B, reused as C (f32) later
  __shared__ float sAI[15];
  __shared__ float sQi[9];
  __shared__ float sAJ[KNB][15];
  __shared__ float sQj[KNB][9];
  __shared__ int   sOffI[KNB];
  __shared__ float sChain[KNB];
  __shared__ float sMaskJ[KNB];
  __shared__ float sDn[KNB];

  int bi  = blockIdx.x;
  int b   = bi >> 10;
  int tid = threadIdx.x;

  if (tid < KNB){
    int j  = wIdx[bi*KNB + tid];
    int gj = (b << 10) + j;
    const float* pj = X + (size_t)gj * 12;
    #pragma unroll
    for (int t = 0; t < 12; ++t) sAJ[tid][t] = pj[t];
    sAJ[tid][12] = wCb[(size_t)gj*3 + 0];
    sAJ[tid][13] = wCb[(size_t)gj*3 + 1];
    sAJ[tid][14] = wCb[(size_t)gj*3 + 2];
    #pragma unroll
    for (int t = 0; t < 9; ++t) sQj[tid][t] = wQ[(size_t)gj*9 + t];
    sOffI[tid]  = resi[bi] - resi[gj];
    sChain[tid] = (chain[bi] == chain[gj]) ? 1.f : 0.f;
    sMaskJ[tid] = mask[gj];
    sDn[tid]    = wDn[bi*KNB + tid];
  } else if (tid == KNB){
    const float* pi = X + (size_t)bi * 12;
    #pragma unroll
    for (int t = 0; t < 12; ++t) sAI[t] = pi[t];
    sAI[12] = wCb[(size_t)bi*3 + 0];
    sAI[13] = wCb[(size_t)bi*3 + 1];
    sAI[14] = wCb[(size_t)bi*3 + 2];
  } else if (tid == KNB + 1){
    #pragma unroll
    for (int t = 0; t < 9; ++t) sQi[t] = wQ[(size_t)bi*9 + t];
  }
  // zero pad: rows 30,31 (448 cols) and cols 434..447 of rows 0..29
  for (int e = tid; e < 2*KP; e += 256) As[30*ASTR + (e >= KP ? ASTR + e - KP : e)] = 0;
  for (int e = tid; e < KNB*14; e += 256){
    int r = e / 14, c = EIN + (e % 14);
    As[r*ASTR + c] = 0;
  }
  __syncthreads();

  // Phase A: 30 edges x 8 subtasks, writing bf16 features edge-major
  if (tid < KNB*8){
    int k = tid >> 3, s = tid & 7;
    ushort_t* row = &As[k*ASTR];
    if (s == 0){
      int off = sOffI[k];
      float ch = sChain[k];
      int d = off + 32;
      d = d < 0 ? 0 : (d > 64 ? 64 : d);
      if (!(ch > 0.5f)) d = 65;
      #pragma unroll
      for (int m2 = 0; m2 < 16; ++m2)
        row[m2] = f2bf(Wp[d*16 + m2] + bp[m2]);
      row[432] = f2bf(ch);
      row[433] = f2bf(sMaskJ[k]);
    } else if (s == 1){
      float nx = sAI[0], ny = sAI[1], nz = sAI[2];
      const int amap[4] = {3, 0, 6, 9};
      #pragma unroll
      for (int a = 0; a < 4; ++a){
        float dx = sAJ[k][amap[a]+0] - nx;
        float dy = sAJ[k][amap[a]+1] - ny;
        float dz = sAJ[k][amap[a]+2] - nz;
        float e0 = sQi[0]*dx + sQi[1]*dy + sQi[2]*dz;
        float e1 = sQi[3]*dx + sQi[4]*dy + sQi[5]*dz;
        float e2 = sQi[6]*dx + sQi[7]*dy + sQi[8]*dz;
        float nn = sqrtf(e0*e0 + e1*e1 + e2*e2);
        float inv = nn > 0.f ? 1.f/nn : 0.f;
        row[416 + a*3 + 0] = f2bf(e0*inv);
        row[416 + a*3 + 1] = f2bf(e1*inv);
        row[416 + a*3 + 2] = f2bf(e2*inv);
      }
    } else if (s == 2){
      float R[3][3];
      #pragma unroll
      for (int i2 = 0; i2 < 3; ++i2)
        #pragma unroll
        for (int l2 = 0; l2 < 3; ++l2)
          R[i2][l2] = sQi[0*3+i2]*sQj[k][0*3+l2]
                    + sQi[1*3+i2]*sQj[k][1*3+l2]
                    + sQi[2*3+i2]*sQj[k][2*3+l2];
      float Rxx = R[0][0], Ryy = R[1][1], Rzz = R[2][2];
      float mx = 0.5f*sqrtf(fabsf(1.f + Rxx - Ryy - Rzz));
      float my = 0.5f*sqrtf(fabsf(1.f - Rxx + Ryy - Rzz));
      float mz = 0.5f*sqrtf(fabsf(1.f - Rxx - Ryy + Rzz));
      float qx = fsign(R[2][1] - R[1][2]) * mx;
      float qy = fsign(R[0][2] - R[2][0]) * my;
      float qz = fsign(R[1][0] - R[0][1]) * mz;
      float qw = sqrtf(fmaxf(1.f + Rxx + Ryy + Rzz, 0.f)) * 0.5f;
      float qn = sqrtf(qx*qx + qy*qy + qz*qz + qw*qw);
      float inv = qn > 0.f ? 1.f/qn : 0.f;
      row[428] = f2bf(qx*inv);
      row[429] = f2bf(qy*inv);
      row[430] = f2bf(qz*inv);
      row[431] = f2bf(qw*inv);
    }
    for (int p = s; p < 25; p += 8){
      float d;
      if (p == 0) d = sDn[k];
      else {
        int ai = c_pa[p-1]*3, bj = c_pb[p-1]*3;
        float dx = sAI[ai+0] - sAJ[k][bj+0];
        float dy = sAI[ai+1] - sAJ[k][bj+1];
        float dz = sAI[ai+2] - sAJ[k][bj+2];
        d = sqrtf(dx*dx + dy*dy + dz*dz + 1e-6f);
      }
      #pragma unroll
      for (int m2 = 0; m2 < 16; ++m2){
        float mu = (float)(2.0 + m2 * (20.0/15.0));
        float tt = (d - mu) * 0.8f;
        row[16 + p*16 + m2] = f2bf(expf(-tt*tt));
      }
    }
  }
  __syncthreads();

  // Phase B: MFMA. wave w owns ntiles {2w,2w+1} x mtiles {0,1}
  int w = tid >> 6, l = tid & 63;
  int n0 = w*2;
  int aOff0 = (l & 15)*ASTR + (l >> 4)*8;
  int aOff1 = aOff0 + 16*ASTR;
  const ushort_t* bp0 = Wfrag + ((size_t)(n0    *KST)*64 + l)*8;
  const ushort_t* bp1 = Wfrag + ((size_t)((n0+1)*KST)*64 + l)*8;

  f32x4 acc00 = {0.f,0.f,0.f,0.f}, acc01 = acc00, acc10 = acc00, acc11 = acc00;

  bf16x8 a0 = *(const bf16x8*)&As[aOff0];
  bf16x8 a1 = *(const bf16x8*)&As[aOff1];
  bf16x8 b0 = *(const bf16x8*)bp0;
  bf16x8 b1 = *(const bf16x8*)bp1;
  #pragma unroll
  for (int s = 0; s < KST; ++s){
    bf16x8 a0n, a1n, b0n, b1n;
    if (s < KST-1){
      int ka = (s+1)*32;
      a0n = *(const bf16x8*)&As[aOff0 + ka];
      a1n = *(const bf16x8*)&As[aOff1 + ka];
      b0n = *(const bf16x8*)(bp0 + (size_t)(s+1)*64*8);
      b1n = *(const bf16x8*)(bp1 + (size_t)(s+1)*64*8);
    }
    acc00 = __builtin_amdgcn_mfma_f32_16x16x32_bf16(a0, b0, acc00, 0, 0, 0);
    acc01 = __builtin_amdgcn_mfma_f32_16x16x32_bf16(a0, b1, acc01, 0, 0, 0);
    acc10 = __builtin_amdgcn_mfma_f32_16x16x32_bf16(a1, b0, acc10, 0, 0, 0);
    acc11 = __builtin_amdgcn_mfma_f32_16x16x32_bf16(a1, b1, acc11, 0, 0, 0);
    if (s < KST-1){ a0 = a0n; a1 = a1n; b0 = b0n; b1 = b1n; }
  }
  __syncthreads();   // all As reads done; reuse as C tile

  float* Cs = (float*)As;       // [32][CSTR]
  int ccol = l & 15, crow = (l >> 4)*4;
  #pragma unroll
  for (int r = 0; r < 4; ++r){
    Cs[(crow + r)*CSTR      + n0*16 + ccol]      = acc00[r];
    Cs[(crow + r)*CSTR      + (n0+1)*16 + ccol]  = acc01[r];
    Cs[(16 + crow + r)*CSTR + n0*16 + ccol]      = acc10[r];
    Cs[(16 + crow + r)*CSTR + (n0+1)*16 + ccol]  = acc11[r];
  }
  __syncthreads();

  // LayerNorm: 8 threads per edge row, 16 channels each
  if (tid < KNB*8){
    int row = tid >> 3, g = tid & 7;
    float v[16];
    #pragma unroll
    for (int c = 0; c < 16; ++c) v[c] = Cs[row*CSTR + g*16 + c];
    float s = 0.f;
    #pragma unroll
    for (int c = 0; c < 16; ++c) s += v[c];
    #pragma unroll
    for (int off = 1; off < 8; off <<= 1) s += __shfl_xor(s, off, 8);
    float mu = s * (1.f/128.f);
    float vs = 0.f;
    #pragma unroll
    for (int c = 0; c < 16; ++c){ float dd = v[c] - mu; vs += dd*dd; }
    #pragma unroll
    for (int off = 1; off < 8; off <<= 1) vs += __shfl_xor(vs, off, 8);
    float inv = 1.f / sqrtf(vs * (1.f/128.f) + 1e-5f);
    float o[16];
    #pragma unroll
    for (int c = 0; c < 16; ++c)
      o[c] = (v[c] - mu)*inv*ge[g*16 + c] + be[g*16 + c];
    float4* dst = (float4*)&outE[((size_t)bi*KNB + row)*CH + g*16];
    dst[0] = make_float4(o[0], o[1], o[2], o[3]);
    dst[1] = make_float4(o[4], o[5], o[6], o[7]);
    dst[2] = make_float4(o[8], o[9], o[10], o[11]);
    dst[3] = make_float4(o[12], o[13], o[14], o[15]);
  }
}

extern "C" void kernel_launch(void* const* d_in, const int* in_sizes, int n_in,
                              void* d_out, int out_size, void* d_ws, size_t ws_size,
                              hipStream_t stream)
{
  const float* X    = (const float*)d_in[0];
  const float* mask = (const float*)d_in[1];
  const int*   resi = (const int*)  d_in[2];
  const int*   chn  = (const int*)  d_in[3];
  const float* Wp   = (const float*)d_in[4];
  const float* bp   = (const float*)d_in[5];
  const float* We   = (const float*)d_in[6];
  const float* Wn   = (const float*)d_in[7];
  const float* ge   = (const float*)d_in[8];
  const float* be   = (const float*)d_in[9];
  const float* gn   = (const float*)d_in[10];
  const float* bn   = (const float*)d_in[11];

  float* outV = (float*)d_out;                          // (4,1024,128)
  float* outE = outV + (size_t)BATCH*LEN*CH;            // (4,1024,30,128)
  float* outI = outE + (size_t)BATCH*LEN*KNB*CH;        // (4,1024,30) as float

  float* ws   = (float*)d_ws;
  float* wCb  = ws;                                     // 4096*3
  float* wQ   = wCb + (size_t)BATCH*LEN*3;              // 4096*9
  float* wVn  = wQ  + (size_t)BATCH*LEN*9;              // 4096*22
  float* wDn  = wVn + (size_t)BATCH*LEN*22;             // 4096*30
  int*   wIdx = (int*)(wDn + (size_t)BATCH*LEN*KNB);    // 4096*30
  float* wCa  = (float*)(wIdx + (size_t)BATCH*LEN*KNB); // 4096*4
  ushort_t* Wfrag = (ushort_t*)(wCa + (size_t)BATCH*LEN*4);  // 8*14*64*8 bf16

  prep_kernel<<<16 + 28, 256, 0, stream>>>(X, mask, We, wCb, wQ, wVn, wCa, Wfrag);
  topk_kernel<<<BATCH*LEN/4, 256, 0, stream>>>(wCa, wDn, wIdx, outI);
  node_kernel<<<BATCH*LEN, 64, 0, stream>>>(wVn, Wn, gn, bn, outV);
  edge_kernel<<<BATCH*LEN, 256, 0, stream>>>(X, mask, resi, chn, Wp, bp, ge, be,
                                             wCb, wQ, wDn, wIdx, Wfrag, outE);
}

// Round 4
// 187.705 us; speedup vs baseline: 3.2562x; 1.3496x over previous
//
#include <hip/hip_runtime.h>

#define BATCH 4
#define LEN   1024
#define KNB   30
#define CH    128
#define EIN   434
#define KP    448      // padded K
#define KST   14       // k-steps of 32
#define ASTR  456      // A row stride in ushorts (padded: 228 words = 4 mod 32 banks)
#define CSTR  132      // C row stride in floats

typedef unsigned short ushort_t;
typedef __attribute__((ext_vector_type(8))) short bf16x8;
typedef __attribute__((ext_vector_type(4))) float f32x4;

// PAIRS atom indices: N=0, Ca=1, C=2, O=3, Cb=4
__constant__ int c_pa[24] = {0,2,3,4,1,1,1,1,0,0,0,4,4,3,0,2,3,4,2,3,4,2,3,2};
__constant__ int c_pb[24] = {0,2,3,4,0,2,3,4,2,3,4,2,3,2,1,1,1,1,0,0,0,4,4,3};

struct F3 { float x, y, z; };
__device__ __forceinline__ F3 f3sub(F3 a, F3 b){ return {a.x-b.x, a.y-b.y, a.z-b.z}; }
__device__ __forceinline__ F3 f3cross(F3 a, F3 b){
  return {a.y*b.z - a.z*b.y, a.z*b.x - a.x*b.z, a.x*b.y - a.y*b.x};
}
__device__ __forceinline__ float f3dot(F3 a, F3 b){ return a.x*b.x + a.y*b.y + a.z*b.z; }
__device__ __forceinline__ F3 f3norm(F3 a){
  float n = sqrtf(f3dot(a,a));
  if (n > 0.f) return {a.x/n, a.y/n, a.z/n};
  return {0.f, 0.f, 0.f};
}
__device__ __forceinline__ float fsign(float x){ return (x > 0.f) ? 1.f : ((x < 0.f) ? -1.f : 0.f); }
__device__ __forceinline__ float clip1(float c){ return fminf(fmaxf(c, -1.f + 1e-7f), 1.f - 1e-7f); }
__device__ __forceinline__ float dihedralf(F3 ua, F3 ub, F3 uc){
  F3 n0 = f3norm(f3cross(ua, ub));
  F3 n1 = f3norm(f3cross(ub, uc));
  float cd = clip1(f3dot(n0, n1));
  F3 v = f3norm(f3cross(n0, n1));
  return fsign(-f3dot(v, ub)) * acosf(cd);
}
__device__ __forceinline__ ushort_t f2bf(float f){
  unsigned u = __float_as_uint(f);
  unsigned r = u + 0x7FFFu + ((u >> 16) & 1u);   // round-to-nearest-even
  return (ushort_t)(r >> 16);
}

// Wave-wide u32 min via DPP (VALU pipe, no DS ops). Result uniform.
#define DPP_MIN_STEP(v, ctrl) do{                                            \
    unsigned t_ = (unsigned)__builtin_amdgcn_update_dpp(                     \
        (int)0xFFFFFFFF, (int)(v), (ctrl), 0xF, 0xF, false);                 \
    (v) = t_ < (v) ? t_ : (v);                                               \
  } while(0)
__device__ __forceinline__ unsigned wave_min_u32(unsigned v){
  DPP_MIN_STEP(v, 0x111);   // row_shr:1
  DPP_MIN_STEP(v, 0x112);   // row_shr:2
  DPP_MIN_STEP(v, 0x114);   // row_shr:4
  DPP_MIN_STEP(v, 0x118);   // row_shr:8
  DPP_MIN_STEP(v, 0x142);   // row_bcast:15
  DPP_MIN_STEP(v, 0x143);   // row_bcast:31
  return (unsigned)__builtin_amdgcn_readlane((int)v, 63);
}

// ---------------------------------------------------------------------------
// Blocks 0..15: per-node prep (Cb, frame Q, node feats, packed Ca).
// Blocks 16..43: pack W_edge into bf16 B-fragment order.
__global__ __launch_bounds__(256) void prep_kernel(
    const float* __restrict__ X, const float* __restrict__ mask,
    const float* __restrict__ We,
    float* __restrict__ wCb, float* __restrict__ wQ, float* __restrict__ wVn,
    float* __restrict__ wCa, ushort_t* __restrict__ Wfrag)
{
  if (blockIdx.x >= 16){
    int f = (blockIdx.x - 16)*256 + threadIdx.x;
    if (f >= 8*KST*64) return;
    int t = f / (KST*64);
    int s = (f / 64) % KST;
    int l = f & 63;
    int n  = t*16 + (l & 15);
    int k0 = s*32 + (l >> 4)*8;
    ushort_t v[8];
    #pragma unroll
    for (int j = 0; j < 8; ++j){
      int k = k0 + j;
      v[j] = (k < EIN) ? f2bf(We[(size_t)k*CH + n]) : (ushort_t)0;
    }
    ulong2* dst = (ulong2*)(Wfrag + (size_t)f*8);
    *dst = *(ulong2*)v;
    return;
  }

  int idx = blockIdx.x * 256 + threadIdx.x;
  int n = idx & (LEN - 1);
  const float* p = X + (size_t)idx * 12;
  F3 Na = {p[0], p[1], p[2]};
  F3 Ca = {p[3], p[4], p[5]};
  F3 Cc = {p[6], p[7], p[8]};
  F3 Oa = {p[9], p[10], p[11]};
  wCa[idx*4+0] = Ca.x; wCa[idx*4+1] = Ca.y; wCa[idx*4+2] = Ca.z; wCa[idx*4+3] = 0.f;
  F3 bv = f3sub(Ca, Na);
  F3 cv = f3sub(Cc, Ca);
  F3 av = f3cross(bv, cv);
  wCb[idx*3+0] = -0.58273431f*av.x + 0.56802827f*bv.x - 0.54067466f*cv.x + Ca.x;
  wCb[idx*3+1] = -0.58273431f*av.y + 0.56802827f*bv.y - 0.54067466f*cv.y + Ca.y;
  wCb[idx*3+2] = -0.58273431f*av.z + 0.56802827f*bv.z - 0.54067466f*cv.z + Ca.z;

  F3 u0 = f3norm(bv);
  F3 u1 = f3norm(cv);

  float Q[9];
  if (n < LEN - 1){
    F3 b1 = f3norm(f3sub(u0, u1));
    F3 n0 = f3norm(f3cross(u0, u1));
    F3 r2 = f3cross(b1, n0);
    Q[0]=b1.x; Q[1]=b1.y; Q[2]=b1.z;
    Q[3]=n0.x; Q[4]=n0.y; Q[5]=n0.z;
    Q[6]=r2.x; Q[7]=r2.y; Q[8]=r2.z;
  } else {
    #pragma unroll
    for (int t = 0; t < 9; ++t) Q[t] = 0.f;
  }
  #pragma unroll
  for (int t = 0; t < 9; ++t) wQ[(size_t)idx*9 + t] = Q[t];

  float m = mask[idx];
  bool hp = (n > 0), hn = (n < LEN - 1);
  F3 um1 = {0,0,0}, u2 = {0,0,0}, u3 = {0,0,0};
  if (hp){
    const float* pp = p - 12;
    F3 Cp = {pp[6], pp[7], pp[8]};
    um1 = f3norm(f3sub(Na, Cp));
  }
  if (hn){
    const float* pn = p + 12;
    F3 Nn  = {pn[0], pn[1], pn[2]};
    F3 Can = {pn[3], pn[4], pn[5]};
    u2 = f3norm(f3sub(Nn, Cc));
    u3 = f3norm(f3sub(Can, Nn));
  }
  float D0=0.f, D1=0.f, D2=0.f, A0=0.f, A1=0.f, A2=0.f;
  if (hp){ D0 = dihedralf(um1, u0, u1); A0 = acosf(clip1(f3dot(um1, u0))); }
  if (hn){
    D1 = dihedralf(u0, u1, u2); A1 = acosf(clip1(f3dot(u0, u1)));
    D2 = dihedralf(u1, u2, u3); A2 = acosf(clip1(f3dot(u1, u2)));
  }
  float vn[22];
  vn[0] = cosf(D0)*m; vn[1] = cosf(D1)*m; vn[2]  = cosf(D2)*m;
  vn[3] = sinf(D0)*m; vn[4] = sinf(D1)*m; vn[5]  = sinf(D2)*m;
  vn[6] = cosf(A0)*m; vn[7] = cosf(A1)*m; vn[8]  = cosf(A2)*m;
  vn[9] = sinf(A0)*m; vn[10]= sinf(A1)*m; vn[11] = sinf(A2)*m;
  F3 dxs[3];
  dxs[0] = {0.f, 0.f, 0.f};
  dxs[1] = f3sub(Cc, Na);
  dxs[2] = f3sub(Oa, Na);
  #pragma unroll
  for (int a = 0; a < 3; ++a){
    F3 dv = dxs[a];
    F3 du = { Q[0]*dv.x + Q[1]*dv.y + Q[2]*dv.z,
              Q[3]*dv.x + Q[4]*dv.y + Q[5]*dv.z,
              Q[6]*dv.x + Q[7]*dv.y + Q[8]*dv.z };
    F3 dn = f3norm(du);
    vn[12 + a*3 + 0] = dn.x * m;
    vn[12 + a*3 + 1] = dn.y * m;
    vn[12 + a*3 + 2] = dn.z * m;
  }
  vn[21] = m;
  #pragma unroll
  for (int t = 0; t < 22; ++t) wVn[(size_t)idx*22 + t] = vn[t];
}

// ---------------------------------------------------------------------------
// Wave-per-node top-30, DPP edition. Per lane: 16 u32 distance keys.
// Round = (1) DPP wave-min of dist bits, (2) DPP wave-min of index among
// lanes at that min -> exact lax.top_k (value, then lower index) order.
// Winner unique (index mod 64 == lane). No LDS, no DS-pipe ops, no barriers.
__global__ __launch_bounds__(256) void topk_kernel(
    const float* __restrict__ wCa, float* __restrict__ wDn,
    int* __restrict__ wIdx, float* __restrict__ outI)
{
  int wid = threadIdx.x >> 6, l = threadIdx.x & 63;
  int bi = blockIdx.x*4 + wid;
  int b  = bi >> 10;
  const float4* Ca = (const float4*)wCa;
  float4 ci = Ca[bi];
  const float4* Cb = Ca + (size_t)b * LEN;

  unsigned D[16];
  #pragma unroll
  for (int t = 0; t < 16; ++t){
    int j = l + 64*t;
    float4 cj = Cb[j];
    float dx = ci.x - cj.x, dy = ci.y - cj.y, dz = ci.z - cj.z;
    D[t] = __float_as_uint(sqrtf(dx*dx + dy*dy + dz*dz + 1e-6f));
  }
  unsigned lmin = D[0]; unsigned jmin = (unsigned)l;
  #pragma unroll
  for (int t = 1; t < 16; ++t)
    if (D[t] < lmin){ lmin = D[t]; jmin = (unsigned)(l + 64*t); }

  for (int k = 0; k < KNB; ++k){
    unsigned dmin = wave_min_u32(lmin);
    unsigned cand = (lmin == dmin) ? jmin : 0xFFFFFFFFu;
    unsigned jwin = wave_min_u32(cand);
    if (cand == jwin){           // unique winner lane
      wIdx[bi*KNB + k] = (int)jwin;
      wDn[bi*KNB + k]  = __uint_as_float(dmin);
      outI[bi*KNB + k] = (float)jwin;
      int tw = (int)(jwin >> 6);
      #pragma unroll
      for (int t = 0; t < 16; ++t) if (t == tw) D[t] = 0xFFFFFFFFu;
      lmin = D[0]; jmin = (unsigned)l;
      #pragma unroll
      for (int t = 1; t < 16; ++t)
        if (D[t] < lmin){ lmin = D[t]; jmin = (unsigned)(l + 64*t); }
    }
  }
}

// ---------------------------------------------------------------------------
// Vn = LN(vn_raw @ W_node) * g + b
__global__ __launch_bounds__(64) void node_kernel(
    const float* __restrict__ wVn, const float* __restrict__ Wn,
    const float* __restrict__ gn, const float* __restrict__ bn,
    float* __restrict__ outV)
{
  int bi = blockIdx.x;
  int t  = threadIdx.x;
  __shared__ float v[22];
  if (t < 22) v[t] = wVn[(size_t)bi*22 + t];
  __syncthreads();
  float x0 = 0.f, x1 = 0.f;
  #pragma unroll
  for (int r = 0; r < 22; ++r){
    float vr = v[r];
    x0 = fmaf(vr, Wn[r*CH + t], x0);
    x1 = fmaf(vr, Wn[r*CH + t + 64], x1);
  }
  float s = x0 + x1;
  #pragma unroll
  for (int off = 1; off < 64; off <<= 1) s += __shfl_xor(s, off);
  float mu = s * (1.f/128.f);
  float d0 = x0 - mu, d1 = x1 - mu;
  float vs = d0*d0 + d1*d1;
  #pragma unroll
  for (int off = 1; off < 64; off <<= 1) vs += __shfl_xor(vs, off);
  float inv = 1.f / sqrtf(vs * (1.f/128.f) + 1e-5f);
  outV[(size_t)bi*CH + t]      = d0*inv*gn[t]    + bn[t];
  outV[(size_t)bi*CH + t + 64] = d1*inv*gn[t+64] + bn[t+64];
}

// ---------------------------------------------------------------------------
// Block per node, 256 threads: build 30x434 features as bf16 A-tile in LDS,
// then MFMA (16x16x32 bf16) vs pre-packed W fragments + LayerNorm epilogue.
__global__ __launch_bounds__(256) void edge_kernel(
    const float* __restrict__ X, const float* __restrict__ mask,
    const int* __restrict__ resi, const int* __restrict__ chain,
    const float* __restrict__ Wp, const float* __restrict__ bp,
    const float* __restrict__ ge, const float* __restrict__ be,
    const float* __restrict__ wCb, const float* __restrict__ wQ,
    const float* __restrict__ wDn, const int* __restrict__ wIdx,
    const ushort_t* __restrict__ Wfrag,
    float* __restrict__ outE)
{
  __shared__ __align__(16) ushort_t As[32*ASTR];   // 29184 B, reused as C (f32) later
  __shared__ float sAI[15];
  __shared__ float sQi[9];
  __shared__ float sAJ[KNB][15];
  __shared__ float sQj[KNB][9];
  __shared__ int   sOffI[KNB];
  __shared__ float sChain[KNB];
  __shared__ float sMaskJ[KNB];
  __shared__ float sDn[KNB];

  int bi  = blockIdx.x;
  int b   = bi >> 10;
  int tid = threadIdx.x;

  if (tid < KNB){
    int j  = wIdx[bi*KNB + tid];
    int gj = (b << 10) + j;
    const float* pj = X + (size_t)gj * 12;
    #pragma unroll
    for (int t = 0; t < 12; ++t) sAJ[tid][t] = pj[t];
    sAJ[tid][12] = wCb[(size_t)gj*3 + 0];
    sAJ[tid][13] = wCb[(size_t)gj*3 + 1];
    sAJ[tid][14] = wCb[(size_t)gj*3 + 2];
    #pragma unroll
    for (int t = 0; t < 9; ++t) sQj[tid][t] = wQ[(size_t)gj*9 + t];
    sOffI[tid]  = resi[bi] - resi[gj];
    sChain[tid] = (chain[bi] == chain[gj]) ? 1.f : 0.f;
    sMaskJ[tid] = mask[gj];
    sDn[tid]    = wDn[bi*KNB + tid];
  } else if (tid == KNB){
    const float* pi = X + (size_t)bi * 12;
    #pragma unroll
    for (int t = 0; t < 12; ++t) sAI[t] = pi[t];
    sAI[12] = wCb[(size_t)bi*3 + 0];
    sAI[13] = wCb[(size_t)bi*3 + 1];
    sAI[14] = wCb[(size_t)bi*3 + 2];
  } else if (tid == KNB + 1){
    #pragma unroll
    for (int t = 0; t < 9; ++t) sQi[t] = wQ[(size_t)bi*9 + t];
  }
  // zero pad: rows 30,31 (448 cols) and cols 434..447 of rows 0..29
  for (int e = tid; e < 2*KP; e += 256) As[30*ASTR + (e >= KP ? ASTR + e - KP : e)] = 0;
  for (int e = tid; e < KNB*14; e += 256){
    int r = e / 14, c = EIN + (e % 14);
    As[r*ASTR + c] = 0;
  }
  __syncthreads();

  // Phase A: 30 edges x 8 subtasks, writing bf16 features edge-major
  if (tid < KNB*8){
    int k = tid >> 3, s = tid & 7;
    ushort_t* row = &As[k*ASTR];
    if (s == 0){
      int off = sOffI[k];
      float ch = sChain[k];
      int d = off + 32;
      d = d < 0 ? 0 : (d > 64 ? 64 : d);
      if (!(ch > 0.5f)) d = 65;
      #pragma unroll
      for (int m2 = 0; m2 < 16; ++m2)
        row[m2] = f2bf(Wp[d*16 + m2] + bp[m2]);
      row[432] = f2bf(ch);
      row[433] = f2bf(sMaskJ[k]);
    } else if (s == 1){
      float nx = sAI[0], ny = sAI[1], nz = sAI[2];
      const int amap[4] = {3, 0, 6, 9};
      #pragma unroll
      for (int a = 0; a < 4; ++a){
        float dx = sAJ[k][amap[a]+0] - nx;
        float dy = sAJ[k][amap[a]+1] - ny;
        float dz = sAJ[k][amap[a]+2] - nz;
        float e0 = sQi[0]*dx + sQi[1]*dy + sQi[2]*dz;
        float e1 = sQi[3]*dx + sQi[4]*dy + sQi[5]*dz;
        float e2 = sQi[6]*dx + sQi[7]*dy + sQi[8]*dz;
        float nn = sqrtf(e0*e0 + e1*e1 + e2*e2);
        float inv = nn > 0.f ? 1.f/nn : 0.f;
        row[416 + a*3 + 0] = f2bf(e0*inv);
        row[416 + a*3 + 1] = f2bf(e1*inv);
        row[416 + a*3 + 2] = f2bf(e2*inv);
      }
    } else if (s == 2){
      float R[3][3];
      #pragma unroll
      for (int i2 = 0; i2 < 3; ++i2)
        #pragma unroll
        for (int l2 = 0; l2 < 3; ++l2)
          R[i2][l2] = sQi[0*3+i2]*sQj[k][0*3+l2]
                    + sQi[1*3+i2]*sQj[k][1*3+l2]
                    + sQi[2*3+i2]*sQj[k][2*3+l2];
      float Rxx = R[0][0], Ryy = R[1][1], Rzz = R[2][2];
      float mx = 0.5f*sqrtf(fabsf(1.f + Rxx - Ryy - Rzz));
      float my = 0.5f*sqrtf(fabsf(1.f - Rxx + Ryy - Rzz));
      float mz = 0.5f*sqrtf(fabsf(1.f - Rxx - Ryy + Rzz));
      float qx = fsign(R[2][1] - R[1][2]) * mx;
      float qy = fsign(R[0][2] - R[2][0]) * my;
      float qz = fsign(R[1][0] - R[0][1]) * mz;
      float qw = sqrtf(fmaxf(1.f + Rxx + Ryy + Rzz, 0.f)) * 0.5f;
      float qn = sqrtf(qx*qx + qy*qy + qz*qz + qw*qw);
      float inv = qn > 0.f ? 1.f/qn : 0.f;
      row[428] = f2bf(qx*inv);
      row[429] = f2bf(qy*inv);
      row[430] = f2bf(qz*inv);
      row[431] = f2bf(qw*inv);
    }
    for (int p = s; p < 25; p += 8){
      float d;
      if (p == 0) d = sDn[k];
      else {
        int ai = c_pa[p-1]*3, bj = c_pb[p-1]*3;
        float dx = sAI[ai+0] - sAJ[k][bj+0];
        float dy = sAI[ai+1] - sAJ[k][bj+1];
        float dz = sAI[ai+2] - sAJ[k][bj+2];
        d = sqrtf(dx*dx + dy*dy + dz*dz + 1e-6f);
      }
      #pragma unroll
      for (int m2 = 0; m2 < 16; ++m2){
        float mu = (float)(2.0 + m2 * (20.0/15.0));
        float tt = (d - mu) * 0.8f;
        row[16 + p*16 + m2] = f2bf(__expf(-tt*tt));
      }
    }
  }
  __syncthreads();

  // Phase B: MFMA. wave w owns ntiles {2w,2w+1} x mtiles {0,1}
  int w = tid >> 6, l = tid & 63;
  int n0 = w*2;
  int aOff0 = (l & 15)*ASTR + (l >> 4)*8;
  int aOff1 = aOff0 + 16*ASTR;
  const ushort_t* bp0 = Wfrag + ((size_t)(n0    *KST)*64 + l)*8;
  const ushort_t* bp1 = Wfrag + ((size_t)((n0+1)*KST)*64 + l)*8;

  f32x4 acc00 = {0.f,0.f,0.f,0.f}, acc01 = acc00, acc10 = acc00, acc11 = acc00;

  bf16x8 a0 = *(const bf16x8*)&As[aOff0];
  bf16x8 a1 = *(const bf16x8*)&As[aOff1];
  bf16x8 b0 = *(const bf16x8*)bp0;
  bf16x8 b1 = *(const bf16x8*)bp1;
  #pragma unroll
  for (int s = 0; s < KST; ++s){
    bf16x8 a0n, a1n, b0n, b1n;
    if (s < KST-1){
      int ka = (s+1)*32;
      a0n = *(const bf16x8*)&As[aOff0 + ka];
      a1n = *(const bf16x8*)&As[aOff1 + ka];
      b0n = *(const bf16x8*)(bp0 + (size_t)(s+1)*64*8);
      b1n = *(const bf16x8*)(bp1 + (size_t)(s+1)*64*8);
    }
    acc00 = __builtin_amdgcn_mfma_f32_16x16x32_bf16(a0, b0, acc00, 0, 0, 0);
    acc01 = __builtin_amdgcn_mfma_f32_16x16x32_bf16(a0, b1, acc01, 0, 0, 0);
    acc10 = __builtin_amdgcn_mfma_f32_16x16x32_bf16(a1, b0, acc10, 0, 0, 0);
    acc11 = __builtin_amdgcn_mfma_f32_16x16x32_bf16(a1, b1, acc11, 0, 0, 0);
    if (s < KST-1){ a0 = a0n; a1 = a1n; b0 = b0n; b1 = b1n; }
  }
  __syncthreads();   // all As reads done; reuse as C tile

  float* Cs = (float*)As;       // [32][CSTR]
  int ccol = l & 15, crow = (l >> 4)*4;
  #pragma unroll
  for (int r = 0; r < 4; ++r){
    Cs[(crow + r)*CSTR      + n0*16 + ccol]      = acc00[r];
    Cs[(crow + r)*CSTR      + (n0+1)*16 + ccol]  = acc01[r];
    Cs[(16 + crow + r)*CSTR + n0*16 + ccol]      = acc10[r];
    Cs[(16 + crow + r)*CSTR + (n0+1)*16 + ccol]  = acc11[r];
  }
  __syncthreads();

  // LayerNorm: 8 threads per edge row, 16 channels each
  if (tid < KNB*8){
    int row = tid >> 3, g = tid & 7;
    float v[16];
    #pragma unroll
    for (int c = 0; c < 16; ++c) v[c] = Cs[row*CSTR + g*16 + c];
    float s = 0.f;
    #pragma unroll
    for (int c = 0; c < 16; ++c) s += v[c];
    #pragma unroll
    for (int off = 1; off < 8; off <<= 1) s += __shfl_xor(s, off, 8);
    float mu = s * (1.f/128.f);
    float vs = 0.f;
    #pragma unroll
    for (int c = 0; c < 16; ++c){ float dd = v[c] - mu; vs += dd*dd; }
    #pragma unroll
    for (int off = 1; off < 8; off <<= 1) vs += __shfl_xor(vs, off, 8);
    float inv = 1.f / sqrtf(vs * (1.f/128.f) + 1e-5f);
    float o[16];
    #pragma unroll
    for (int c = 0; c < 16; ++c)
      o[c] = (v[c] - mu)*inv*ge[g*16 + c] + be[g*16 + c];
    float4* dst = (float4*)&outE[((size_t)bi*KNB + row)*CH + g*16];
    dst[0] = make_float4(o[0], o[1], o[2], o[3]);
    dst[1] = make_float4(o[4], o[5], o[6], o[7]);
    dst[2] = make_float4(o[8], o[9], o[10], o[11]);
    dst[3] = make_float4(o[12], o[13], o[14], o[15]);
  }
}

extern "C" void kernel_launch(void* const* d_in, const int* in_sizes, int n_in,
                              void* d_out, int out_size, void* d_ws, size_t ws_size,
                              hipStream_t stream)
{
  const float* X    = (const float*)d_in[0];
  const float* mask = (const float*)d_in[1];
  const int*   resi = (const int*)  d_in[2];
  const int*   chn  = (const int*)  d_in[3];
  const float* Wp   = (const float*)d_in[4];
  const float* bp   = (const float*)d_in[5];
  const float* We   = (const float*)d_in[6];
  const float* Wn   = (const float*)d_in[7];
  const float* ge   = (const float*)d_in[8];
  const float* be   = (const float*)d_in[9];
  const float* gn   = (const float*)d_in[10];
  const float* bn   = (const float*)d_in[11];

  float* outV = (float*)d_out;                          // (4,1024,128)
  float* outE = outV + (size_t)BATCH*LEN*CH;            // (4,1024,30,128)
  float* outI = outE + (size_t)BATCH*LEN*KNB*CH;        // (4,1024,30) as float

  float* ws   = (float*)d_ws;
  float* wCb  = ws;                                     // 4096*3
  float* wQ   = wCb + (size_t)BATCH*LEN*3;              // 4096*9
  float* wVn  = wQ  + (size_t)BATCH*LEN*9;              // 4096*22
  float* wDn  = wVn + (size_t)BATCH*LEN*22;             // 4096*30
  int*   wIdx = (int*)(wDn + (size_t)BATCH*LEN*KNB);    // 4096*30
  float* wCa  = (float*)(wIdx + (size_t)BATCH*LEN*KNB); // 4096*4
  ushort_t* Wfrag = (ushort_t*)(wCa + (size_t)BATCH*LEN*4);  // 8*14*64*8 bf16

  prep_kernel<<<16 + 28, 256, 0, stream>>>(X, mask, We, wCb, wQ, wVn, wCa, Wfrag);
  topk_kernel<<<BATCH*LEN/4, 256, 0, stream>>>(wCa, wDn, wIdx, outI);
  node_kernel<<<BATCH*LEN, 64, 0, stream>>>(wVn, Wn, gn, bn, outV);
  edge_kernel<<<BATCH*LEN, 256, 0, stream>>>(X, mask, resi, chn, Wp, bp, ge, be,
                                             wCb, wQ, wDn, wIdx, Wfrag, outE);
}